// Round 3
// baseline (328.496 us; speedup 1.0000x reference)
//
#include <hip/hip_runtime.h>
#include <hip/hip_bf16.h>

#define BB 4
#define SS 2048
#define DD 1024
#define HH 16
#define MM (BB * SS)   // 8192

typedef __attribute__((ext_vector_type(8))) short bf16x8;
typedef __attribute__((ext_vector_type(4))) float f32x4;

__device__ __forceinline__ unsigned short f2bf(float f) {
  union { float f; unsigned u; } v; v.f = f;
  unsigned r = v.u + 0x7fffu + ((v.u >> 16) & 1u);
  return (unsigned short)(r >> 16);
}

__device__ __forceinline__ void gl2lds16(const void* g, void* l) {
  __builtin_amdgcn_global_load_lds(
      (const __attribute__((address_space(1))) unsigned int*)g,
      (__attribute__((address_space(3))) unsigned int*)l, 16, 0, 0);
}

// fp32 -> bf16 pre-convert: y<4 -> W[y] (1M each), y>=4 -> X chunk (8M total)
__global__ __launch_bounds__(256)
void convall(const float* __restrict__ X, const float* __restrict__ a,
             const float* __restrict__ b, const float* __restrict__ c,
             const float* __restrict__ d, unsigned short* __restrict__ wall,
             unsigned short* __restrict__ xb) {
  int y = blockIdx.y;
  const float* s; unsigned short* o;
  if (y < 4) {
    const float* srcs[4] = {a, b, c, d};
    s = srcs[y]; o = wall + (size_t)y * 1048576;
  } else {
    s = X + (size_t)(y - 4) * 1048576; o = xb + (size_t)(y - 4) * 1048576;
  }
  int i = (blockIdx.x * 256 + threadIdx.x) * 4;
  float4 v = *(const float4*)(s + i);
  ushort4 h4; h4.x = f2bf(v.x); h4.y = f2bf(v.y); h4.z = f2bf(v.z); h4.w = f2bf(v.w);
  *(ushort4*)(o + i) = h4;
}

// C[m,n] = sum_k A[m,k]*W[n,k].  A bf16, B bf16, both staged via global_load_lds w=16.
// OMODE 1: fp32 C.  OMODE 3: QKV routing (Q bf16 pre-scaled by log2e/8 / K bf16 /
// V -> sigma-permuted V^T, Vt[bh][d][kt*64 + sigma(key)], sigma(key) = (key&15)*4 + (key>>4)).
template<int OMODE>
__global__ __launch_bounds__(256)
void gemm_k(const unsigned short* __restrict__ A16, const unsigned short* __restrict__ Bp,
            void* __restrict__ C0p, void* __restrict__ C1p, void* __restrict__ C2p) {
  __shared__ unsigned short As[32 * 136];  // staging [128][32]; also V^T transpose buf
  __shared__ unsigned short Bs[128 * 32];
  const int m0 = blockIdx.x * 128, n0g = blockIdx.y * 128;
  const int tid = threadIdx.x, lane = tid & 63, wave = tid >> 6;
  const int wm = (wave & 1) * 64, wn = (wave >> 1) * 64;
  const int row_in = lane & 15, quad = lane >> 4;

  f32x4 acc[4][4] = {};

  for (int kb = 0; kb < DD; kb += 32) {
    {
      int r = wave * 32 + (lane >> 2);
      const unsigned short* g = Bp + (size_t)(n0g + r) * DD + kb + (lane & 3) * 8;
      gl2lds16(g, Bs + (wave * 32) * 32);
      gl2lds16(g + (size_t)16 * DD, Bs + (wave * 32 + 16) * 32);
      const unsigned short* ga = A16 + (size_t)(m0 + r) * DD + kb + (lane & 3) * 8;
      gl2lds16(ga, As + (wave * 32) * 32);
      gl2lds16(ga + (size_t)16 * DD, As + (wave * 32 + 16) * 32);
    }
    __syncthreads();
    bf16x8 af[4], bfr[4];
#pragma unroll
    for (int i = 0; i < 4; ++i)
      af[i] = *(const bf16x8*)(As + (wm + i * 16 + row_in) * 32 + quad * 8);
#pragma unroll
    for (int j = 0; j < 4; ++j)
      bfr[j] = *(const bf16x8*)(Bs + (wn + j * 16 + row_in) * 32 + quad * 8);
#pragma unroll
    for (int i = 0; i < 4; ++i)
#pragma unroll
      for (int j = 0; j < 4; ++j)
        acc[i][j] = __builtin_amdgcn_mfma_f32_16x16x32_bf16(af[i], bfr[j], acc[i][j], 0, 0, 0);
    __syncthreads();
  }

  // C/D layout: col = lane&15, row = quad*4 + reg
  if (OMODE == 1) {
    float* Cout = (float*)C0p;
#pragma unroll
    for (int i = 0; i < 4; ++i)
#pragma unroll
      for (int j = 0; j < 4; ++j)
#pragma unroll
        for (int r = 0; r < 4; ++r)
          Cout[(size_t)(m0 + wm + i * 16 + quad * 4 + r) * DD + n0g + wn + j * 16 + row_in] =
              acc[i][j][r];
  } else {
    const int seg = n0g >> 10;
    if (seg < 2) {
      unsigned short* Cout = (unsigned short*)(seg == 0 ? C0p : C1p);
      const int n0 = n0g & 1023;
      // Q gets the softmax log2e/8 scale folded in; K unscaled
      const float scl = (seg == 0) ? 0.180336880f : 1.0f;
#pragma unroll
      for (int i = 0; i < 4; ++i)
#pragma unroll
        for (int j = 0; j < 4; ++j)
#pragma unroll
          for (int r = 0; r < 4; ++r)
            Cout[(size_t)(m0 + wm + i * 16 + quad * 4 + r) * DD + n0 + wn + j * 16 + row_in] =
                f2bf(acc[i][j][r] * scl);
    } else {
      // V^T epilogue -> Vt[bh][d][kt*64 + sigma(key)].  Stored position p holds
      // key sigma^-1(p) = (p&3)*16 + (p>>2): gather cols from the transpose buffer.
      unsigned short* Vt = (unsigned short*)C2p;
      unsigned short* Ts = As;
      const int b = m0 >> 11, m_in_b = m0 & 2047;
      const int nv = n0g - 2048;
#pragma unroll
      for (int cn = 0; cn < 4; ++cn) {
        if ((wave >> 1) == (cn >> 1)) {
#pragma unroll
          for (int i = 0; i < 4; ++i)
#pragma unroll
            for (int jj = 0; jj < 2; ++jj)
#pragma unroll
              for (int r = 0; r < 4; ++r) {
                int j = (cn & 1) * 2 + jj;
                Ts[(jj * 16 + row_in) * 136 + wm + i * 16 + quad * 4 + r] = f2bf(acc[i][j][r]);
              }
        }
        __syncthreads();
#pragma unroll
        for (int it = 0; it < 2; ++it) {
          int cc = tid + it * 256;
          int rowL = cc >> 4, o8 = (cc & 15) * 8;
          int cbase = rowL * 136 + (o8 & 64) + ((o8 & 63) >> 2);
          ushort4 lo, hi;
          lo.x = Ts[cbase];      lo.y = Ts[cbase + 16];
          lo.z = Ts[cbase + 32]; lo.w = Ts[cbase + 48];
          hi.x = Ts[cbase + 1];  hi.y = Ts[cbase + 17];
          hi.z = Ts[cbase + 33]; hi.w = Ts[cbase + 49];
          int n = nv + cn * 32 + rowL;
          int h = n >> 6, dd = n & 63;
          unsigned short* dst = Vt + ((size_t)((b * 16 + h) * 64 + dd)) * SS + m_in_b + o8;
          *(ushort4*)dst = lo;
          *(ushort4*)(dst + 4) = hi;
        }
        __syncthreads();
      }
    }
  }
}

// Flash attention R3: R1 shell (128 q-rows/block, 4 waves x 32 q, 4 blocks/CU) +
// slimmed softmax: Q pre-scaled by log2e/8 in the QKV GEMM and the C0 shift dropped
// (cancels in the softmax ratio) -> p = exp2(sacc) directly; P->bf16 pack via
// v_cvt_pk_bf16_f32 (2 instrs) instead of bias-add + v_perm (6 instrs).
// V sigma-pre-permuted in global; wave-private P stripes; AO in-place over Q.
__global__ __launch_bounds__(256, 4)
void attn_kernel(const unsigned short* __restrict__ Q, const unsigned short* __restrict__ K,
                 const unsigned short* __restrict__ Vt_g, unsigned short* __restrict__ AO) {
  __shared__ unsigned short Ks[64 * 72];   // [key][d]
  __shared__ unsigned short Vs[64 * 72];   // [d][sigma(key)]
  __shared__ unsigned short Ps[128 * 72];  // [q perm][sigma(key)]
  // linear dispatch id (x-fastest); xcd = L&7 is the HW round-robin slot.
  // qt = j&15, bh = (L&7) + 8*(j>>4)  (bijective; all qt of a bh share L mod 8)
  const int L = (blockIdx.y << 4) + blockIdx.x;
  const int jj = L >> 3;
  const int qt = jj & 15;
  const int bh = (L & 7) + ((jj >> 4) << 3);
  const int b = bh >> 4, h = bh & 15;
  const int tid = threadIdx.x, lane = tid & 63, w = tid >> 6;
  const int row_in = lane & 15, quad = lane >> 4;
  const size_t qbase = ((size_t)(b * SS + qt * 128)) * DD + h * 64;

  bf16x8 aq[2][2];
#pragma unroll
  for (int m = 0; m < 2; ++m) {
    const unsigned short* qp = Q + qbase + (size_t)(w * 32 + m * 16 + row_in) * DD;
    aq[m][0] = *(const bf16x8*)(qp + quad * 8);
    aq[m][1] = *(const bf16x8*)(qp + 32 + quad * 8);
  }
  f32x4 oacc[2][4] = {};
  float lrow[2][4] = {};
  const int permr = 2 * (row_in >> 2) + (row_in & 1) + 8 * ((row_in >> 1) & 1);
  const int pw_base = (w * 32) * 72;

  // staging coords (thread-invariant): chunk c -> r = c>>3, o8 = (c&7)*8
  const int r0 = tid >> 3, o80 = (tid & 7) * 8;
  const int r1 = (tid + 256) >> 3, o81 = o80;  // (tid+256)&7 == tid&7
  const unsigned short* kp0 = K + ((size_t)(b * SS + r0)) * DD + h * 64 + o80;
  const unsigned short* kp1 = K + ((size_t)(b * SS + r1)) * DD + h * 64 + o81;
  const unsigned short* vp0 = Vt_g + ((size_t)(bh * 64 + r0)) * SS + o80;
  const unsigned short* vp1 = Vt_g + ((size_t)(bh * 64 + r1)) * SS + o81;

  // prologue prefetch kt=0
  uint4 kr0 = *(const uint4*)kp0;
  uint4 kr1 = *(const uint4*)kp1;
  uint4 vr0 = *(const uint4*)vp0;
  uint4 vr1 = *(const uint4*)vp1;

  for (int kt = 0; kt < SS / 64; ++kt) {
    __syncthreads();               // all waves done reading Ks/Vs of kt-1
    *(uint4*)(Ks + r0 * 72 + o80) = kr0;
    *(uint4*)(Ks + r1 * 72 + o81) = kr1;
    *(uint4*)(Vs + r0 * 72 + o80) = vr0;
    *(uint4*)(Vs + r1 * 72 + o81) = vr1;
    __syncthreads();               // staging visible
    if (kt + 1 < SS / 64) {
      // issue kt+1 loads now; they fly under the whole compute phase
      const size_t ko = (size_t)(kt + 1) * 64 * DD;
      const size_t vo = (size_t)(kt + 1) * 64;
      kr0 = *(const uint4*)(kp0 + ko);
      kr1 = *(const uint4*)(kp1 + ko);
      vr0 = *(const uint4*)(vp0 + vo);
      vr1 = *(const uint4*)(vp1 + vo);
    }

    // S = Q K^T : 32q x 64key per wave (Q carries the log2e/8 scale)
    f32x4 sacc[2][4] = {};
    __builtin_amdgcn_s_setprio(1);
#pragma unroll
    for (int n = 0; n < 4; ++n) {
      bf16x8 bk0 = *(const bf16x8*)(Ks + (n * 16 + row_in) * 72 + quad * 8);
      bf16x8 bk1 = *(const bf16x8*)(Ks + (n * 16 + row_in) * 72 + 32 + quad * 8);
#pragma unroll
      for (int m = 0; m < 2; ++m) {
        sacc[m][n] = __builtin_amdgcn_mfma_f32_16x16x32_bf16(aq[m][0], bk0, sacc[m][n], 0, 0, 0);
        sacc[m][n] = __builtin_amdgcn_mfma_f32_16x16x32_bf16(aq[m][1], bk1, sacc[m][n], 0, 0, 0);
      }
    }
    __builtin_amdgcn_s_setprio(0);

    // softmax: p = exp2(s); writer's keys {n*16+row_in} land at sigma = row_in*4+n
    // -> one b64 write per (m,r).  cvt_pk packs [lo=S0, hi=S1] = [p_even, p_odd].
#pragma unroll
    for (int m = 0; m < 2; ++m)
#pragma unroll
      for (int r = 0; r < 4; ++r) {
        int prow = pw_base + (m * 16 + 2 * quad + (r & 1) + 8 * ((r >> 1) & 1)) * 72;
        float p0 = __builtin_amdgcn_exp2f(sacc[m][0][r]);
        float p1 = __builtin_amdgcn_exp2f(sacc[m][1][r]);
        float p2 = __builtin_amdgcn_exp2f(sacc[m][2][r]);
        float p3 = __builtin_amdgcn_exp2f(sacc[m][3][r]);
        lrow[m][r] += (p0 + p1) + (p2 + p3);
        unsigned w01, w23;
        asm("v_cvt_pk_bf16_f32 %0, %1, %2" : "=v"(w01) : "v"(p0), "v"(p1));
        asm("v_cvt_pk_bf16_f32 %0, %1, %2" : "=v"(w23) : "v"(p2), "v"(p3));
        *(uint2*)(Ps + prow + row_in * 4) = make_uint2(w01, w23);
      }

    // O += P V over sigma-space (wave-private P rows -> no barrier)
    __builtin_amdgcn_s_setprio(1);
#pragma unroll
    for (int c = 0; c < 2; ++c) {
      bf16x8 ap0 = *(const bf16x8*)(Ps + pw_base + (permr) * 72 + c * 32 + quad * 8);
      bf16x8 ap1 = *(const bf16x8*)(Ps + pw_base + (16 + permr) * 72 + c * 32 + quad * 8);
#pragma unroll
      for (int t = 0; t < 4; ++t) {
        bf16x8 bv = *(const bf16x8*)(Vs + (t * 16 + row_in) * 72 + c * 32 + quad * 8);
        oacc[0][t] = __builtin_amdgcn_mfma_f32_16x16x32_bf16(ap0, bv, oacc[0][t], 0, 0, 0);
        oacc[1][t] = __builtin_amdgcn_mfma_f32_16x16x32_bf16(ap1, bv, oacc[1][t], 0, 0, 0);
      }
    }
    __builtin_amdgcn_s_setprio(0);
  }

#pragma unroll
  for (int m = 0; m < 2; ++m)
#pragma unroll
    for (int r = 0; r < 4; ++r) {
#pragma unroll
      for (int s = 1; s < 16; s <<= 1) lrow[m][r] += __shfl_xor(lrow[m][r], s, 64);
      float inv = 1.0f / lrow[m][r];
#pragma unroll
      for (int t = 0; t < 4; ++t)
        AO[qbase + (size_t)(w * 32 + m * 16 + quad * 4 + r) * DD + t * 16 + row_in] =
            f2bf(oacc[m][t][r] * inv);
    }
}

extern "C" void kernel_launch(void* const* d_in, const int* in_sizes, int n_in,
                              void* d_out, int out_size, void* d_ws, size_t ws_size,
                              hipStream_t stream) {
  const float* X  = (const float*)d_in[0];
  const float* Wq = (const float*)d_in[1];
  const float* Wk = (const float*)d_in[2];
  const float* Wv = (const float*)d_in[3];
  const float* Wo = (const float*)d_in[4];

  unsigned short* ws   = (unsigned short*)d_ws;
  unsigned short* Qb   = ws;                           // 16 MiB — also AO
  unsigned short* Kb   = Qb + (size_t)MM * DD;         // 16 MiB
  unsigned short* Vtb  = Kb + (size_t)MM * DD;         // 16 MiB, [bh][d][sigma(s)]
  unsigned short* Wall = Vtb + (size_t)MM * DD;        // 8 MiB (Wq,Wk,Wv,Wo bf16)
  unsigned short* Xb   = (unsigned short*)d_out;       // 16 MiB scratch inside d_out
  float* out = (float*)d_out;

  convall<<<dim3(1024, 12), 256, 0, stream>>>(X, Wq, Wk, Wv, Wo, Wall, Xb);

  gemm_k<3><<<dim3(MM / 128, 24), 256, 0, stream>>>(Xb, Wall, Qb, Kb, Vtb);

  attn_kernel<<<dim3(SS / 128, BB * HH), 256, 0, stream>>>(Qb, Kb, Vtb, Qb);

  gemm_k<1><<<dim3(MM / 128, 8), 256, 0, stream>>>(Qb, Wall + (size_t)3 * 1048576,
                                                   out, nullptr, nullptr);
}

// Round 4
// 267.946 us; speedup vs baseline: 1.2260x; 1.2260x over previous
//
#include <hip/hip_runtime.h>
#include <hip/hip_bf16.h>

#define BB 4
#define SS 2048
#define DD 1024
#define HH 16
#define MM (BB * SS)   // 8192

typedef __attribute__((ext_vector_type(8))) short bf16x8;
typedef __attribute__((ext_vector_type(4))) float f32x4;

__device__ __forceinline__ unsigned short f2bf(float f) {
  union { float f; unsigned u; } v; v.f = f;
  unsigned r = v.u + 0x7fffu + ((v.u >> 16) & 1u);
  return (unsigned short)(r >> 16);
}

__device__ __forceinline__ void gl2lds16(const void* g, void* l) {
  __builtin_amdgcn_global_load_lds(
      (const __attribute__((address_space(1))) unsigned int*)g,
      (__attribute__((address_space(3))) unsigned int*)l, 16, 0, 0);
}

// fp32 -> bf16 pre-convert: y<4 -> W[y] (1M each), y>=4 -> X chunk (8M total).
// Wq (y==0) is pre-scaled by log2e/8: folds the softmax 1/sqrt(DK) and ln->log2
// conversion into the QKV GEMM's Q output at zero cost (this kernel is HBM-bound).
__global__ __launch_bounds__(256)
void convall(const float* __restrict__ X, const float* __restrict__ a,
             const float* __restrict__ b, const float* __restrict__ c,
             const float* __restrict__ d, unsigned short* __restrict__ wall,
             unsigned short* __restrict__ xb) {
  int y = blockIdx.y;
  const float* s; unsigned short* o; float scl = 1.0f;
  if (y < 4) {
    const float* srcs[4] = {a, b, c, d};
    s = srcs[y]; o = wall + (size_t)y * 1048576;
    if (y == 0) scl = 0.180336880f;   // log2e / 8
  } else {
    s = X + (size_t)(y - 4) * 1048576; o = xb + (size_t)(y - 4) * 1048576;
  }
  int i = (blockIdx.x * 256 + threadIdx.x) * 4;
  float4 v = *(const float4*)(s + i);
  ushort4 h4;
  h4.x = f2bf(v.x * scl); h4.y = f2bf(v.y * scl);
  h4.z = f2bf(v.z * scl); h4.w = f2bf(v.w * scl);
  *(ushort4*)(o + i) = h4;
}

// C[m,n] = sum_k A[m,k]*W[n,k].  A bf16, B bf16, both staged via global_load_lds w=16.
// OMODE 1: fp32 C.  OMODE 3: QKV routing (Q bf16 / K bf16 / V -> sigma-permuted V^T,
// Vt[bh][d][kt*64 + sigma(key)], sigma(key) = (key&15)*4 + (key>>4)).
template<int OMODE>
__global__ __launch_bounds__(256)
void gemm_k(const unsigned short* __restrict__ A16, const unsigned short* __restrict__ Bp,
            void* __restrict__ C0p, void* __restrict__ C1p, void* __restrict__ C2p) {
  __shared__ unsigned short As[32 * 136];  // staging [128][32]; also V^T transpose buf
  __shared__ unsigned short Bs[128 * 32];
  const int m0 = blockIdx.x * 128, n0g = blockIdx.y * 128;
  const int tid = threadIdx.x, lane = tid & 63, wave = tid >> 6;
  const int wm = (wave & 1) * 64, wn = (wave >> 1) * 64;
  const int row_in = lane & 15, quad = lane >> 4;

  f32x4 acc[4][4] = {};

  for (int kb = 0; kb < DD; kb += 32) {
    {
      int r = wave * 32 + (lane >> 2);
      const unsigned short* g = Bp + (size_t)(n0g + r) * DD + kb + (lane & 3) * 8;
      gl2lds16(g, Bs + (wave * 32) * 32);
      gl2lds16(g + (size_t)16 * DD, Bs + (wave * 32 + 16) * 32);
      const unsigned short* ga = A16 + (size_t)(m0 + r) * DD + kb + (lane & 3) * 8;
      gl2lds16(ga, As + (wave * 32) * 32);
      gl2lds16(ga + (size_t)16 * DD, As + (wave * 32 + 16) * 32);
    }
    __syncthreads();
    bf16x8 af[4], bfr[4];
#pragma unroll
    for (int i = 0; i < 4; ++i)
      af[i] = *(const bf16x8*)(As + (wm + i * 16 + row_in) * 32 + quad * 8);
#pragma unroll
    for (int j = 0; j < 4; ++j)
      bfr[j] = *(const bf16x8*)(Bs + (wn + j * 16 + row_in) * 32 + quad * 8);
#pragma unroll
    for (int i = 0; i < 4; ++i)
#pragma unroll
      for (int j = 0; j < 4; ++j)
        acc[i][j] = __builtin_amdgcn_mfma_f32_16x16x32_bf16(af[i], bfr[j], acc[i][j], 0, 0, 0);
    __syncthreads();
  }

  // C/D layout: col = lane&15, row = quad*4 + reg
  if (OMODE == 1) {
    float* Cout = (float*)C0p;
#pragma unroll
    for (int i = 0; i < 4; ++i)
#pragma unroll
      for (int j = 0; j < 4; ++j)
#pragma unroll
        for (int r = 0; r < 4; ++r)
          Cout[(size_t)(m0 + wm + i * 16 + quad * 4 + r) * DD + n0g + wn + j * 16 + row_in] =
              acc[i][j][r];
  } else {
    const int seg = n0g >> 10;
    if (seg < 2) {
      unsigned short* Cout = (unsigned short*)(seg == 0 ? C0p : C1p);
      const int n0 = n0g & 1023;
#pragma unroll
      for (int i = 0; i < 4; ++i)
#pragma unroll
        for (int j = 0; j < 4; ++j)
#pragma unroll
          for (int r = 0; r < 4; ++r)
            Cout[(size_t)(m0 + wm + i * 16 + quad * 4 + r) * DD + n0 + wn + j * 16 + row_in] =
                f2bf(acc[i][j][r]);
    } else {
      // V^T epilogue -> Vt[bh][d][kt*64 + sigma(key)].  Stored position p holds
      // key sigma^-1(p) = (p&3)*16 + (p>>2): gather cols from the transpose buffer.
      unsigned short* Vt = (unsigned short*)C2p;
      unsigned short* Ts = As;
      const int b = m0 >> 11, m_in_b = m0 & 2047;
      const int nv = n0g - 2048;
#pragma unroll
      for (int cn = 0; cn < 4; ++cn) {
        if ((wave >> 1) == (cn >> 1)) {
#pragma unroll
          for (int i = 0; i < 4; ++i)
#pragma unroll
            for (int jj = 0; jj < 2; ++jj)
#pragma unroll
              for (int r = 0; r < 4; ++r) {
                int j = (cn & 1) * 2 + jj;
                Ts[(jj * 16 + row_in) * 136 + wm + i * 16 + quad * 4 + r] = f2bf(acc[i][j][r]);
              }
        }
        __syncthreads();
#pragma unroll
        for (int it = 0; it < 2; ++it) {
          int cc = tid + it * 256;
          int rowL = cc >> 4, o8 = (cc & 15) * 8;
          int cbase = rowL * 136 + (o8 & 64) + ((o8 & 63) >> 2);
          ushort4 lo, hi;
          lo.x = Ts[cbase];      lo.y = Ts[cbase + 16];
          lo.z = Ts[cbase + 32]; lo.w = Ts[cbase + 48];
          hi.x = Ts[cbase + 1];  hi.y = Ts[cbase + 17];
          hi.z = Ts[cbase + 33]; hi.w = Ts[cbase + 49];
          int n = nv + cn * 32 + rowL;
          int h = n >> 6, dd = n & 63;
          unsigned short* dst = Vt + ((size_t)((b * 16 + h) * 64 + dd)) * SS + m_in_b + o8;
          *(ushort4*)dst = lo;
          *(ushort4*)(dst + 4) = hi;
        }
        __syncthreads();
      }
    }
  }
}

// Flash attention R4: R1 shell (128 q-rows/block, 4 waves x 32 q, 4 blocks/CU).
// Q arrives pre-scaled by log2e/8 (folded into Wq in convall) and the constant
// softmax shift cancels in the ratio -> p = exp2(sacc) directly (no fmaf).
// P->bf16 pack via the compiler-friendly bias-add + v_perm idiom (NOT inline-asm
// cvt_pk: learn_hip m240 measured -37% for the asm form).
// V sigma-pre-permuted in global; wave-private P stripes; AO in-place over Q.
__global__ __launch_bounds__(256, 4)
void attn_kernel(const unsigned short* __restrict__ Q, const unsigned short* __restrict__ K,
                 const unsigned short* __restrict__ Vt_g, unsigned short* __restrict__ AO) {
  __shared__ unsigned short Ks[64 * 72];   // [key][d]
  __shared__ unsigned short Vs[64 * 72];   // [d][sigma(key)]
  __shared__ unsigned short Ps[128 * 72];  // [q perm][sigma(key)]
  // linear dispatch id (x-fastest); xcd = L&7 is the HW round-robin slot.
  // qt = j&15, bh = (L&7) + 8*(j>>4)  (bijective; all qt of a bh share L mod 8)
  const int L = (blockIdx.y << 4) + blockIdx.x;
  const int jj = L >> 3;
  const int qt = jj & 15;
  const int bh = (L & 7) + ((jj >> 4) << 3);
  const int b = bh >> 4, h = bh & 15;
  const int tid = threadIdx.x, lane = tid & 63, w = tid >> 6;
  const int row_in = lane & 15, quad = lane >> 4;
  const size_t qbase = ((size_t)(b * SS + qt * 128)) * DD + h * 64;

  bf16x8 aq[2][2];
#pragma unroll
  for (int m = 0; m < 2; ++m) {
    const unsigned short* qp = Q + qbase + (size_t)(w * 32 + m * 16 + row_in) * DD;
    aq[m][0] = *(const bf16x8*)(qp + quad * 8);
    aq[m][1] = *(const bf16x8*)(qp + 32 + quad * 8);
  }
  f32x4 oacc[2][4] = {};
  float lrow[2][4] = {};
  const int permr = 2 * (row_in >> 2) + (row_in & 1) + 8 * ((row_in >> 1) & 1);
  const int pw_base = (w * 32) * 72;

  // staging coords (thread-invariant): chunk c -> r = c>>3, o8 = (c&7)*8
  const int r0 = tid >> 3, o80 = (tid & 7) * 8;
  const int r1 = (tid + 256) >> 3, o81 = o80;  // (tid+256)&7 == tid&7
  const unsigned short* kp0 = K + ((size_t)(b * SS + r0)) * DD + h * 64 + o80;
  const unsigned short* kp1 = K + ((size_t)(b * SS + r1)) * DD + h * 64 + o81;
  const unsigned short* vp0 = Vt_g + ((size_t)(bh * 64 + r0)) * SS + o80;
  const unsigned short* vp1 = Vt_g + ((size_t)(bh * 64 + r1)) * SS + o81;

  // prologue prefetch kt=0
  uint4 kr0 = *(const uint4*)kp0;
  uint4 kr1 = *(const uint4*)kp1;
  uint4 vr0 = *(const uint4*)vp0;
  uint4 vr1 = *(const uint4*)vp1;

  for (int kt = 0; kt < SS / 64; ++kt) {
    __syncthreads();               // all waves done reading Ks/Vs of kt-1
    *(uint4*)(Ks + r0 * 72 + o80) = kr0;
    *(uint4*)(Ks + r1 * 72 + o81) = kr1;
    *(uint4*)(Vs + r0 * 72 + o80) = vr0;
    *(uint4*)(Vs + r1 * 72 + o81) = vr1;
    __syncthreads();               // staging visible
    if (kt + 1 < SS / 64) {
      // issue kt+1 loads now; they fly under the whole compute phase
      const size_t ko = (size_t)(kt + 1) * 64 * DD;
      const size_t vo = (size_t)(kt + 1) * 64;
      kr0 = *(const uint4*)(kp0 + ko);
      kr1 = *(const uint4*)(kp1 + ko);
      vr0 = *(const uint4*)(vp0 + vo);
      vr1 = *(const uint4*)(vp1 + vo);
    }

    // S = Q K^T : 32q x 64key per wave (Q carries the log2e/8 scale)
    f32x4 sacc[2][4] = {};
    __builtin_amdgcn_s_setprio(1);
#pragma unroll
    for (int n = 0; n < 4; ++n) {
      bf16x8 bk0 = *(const bf16x8*)(Ks + (n * 16 + row_in) * 72 + quad * 8);
      bf16x8 bk1 = *(const bf16x8*)(Ks + (n * 16 + row_in) * 72 + 32 + quad * 8);
#pragma unroll
      for (int m = 0; m < 2; ++m) {
        sacc[m][n] = __builtin_amdgcn_mfma_f32_16x16x32_bf16(aq[m][0], bk0, sacc[m][n], 0, 0, 0);
        sacc[m][n] = __builtin_amdgcn_mfma_f32_16x16x32_bf16(aq[m][1], bk1, sacc[m][n], 0, 0, 0);
      }
    }
    __builtin_amdgcn_s_setprio(0);

    // softmax: p = exp2(s); writer's keys {n*16+row_in} land at sigma = row_in*4+n
    // -> one b64 write per (m,r)
#pragma unroll
    for (int m = 0; m < 2; ++m)
#pragma unroll
      for (int r = 0; r < 4; ++r) {
        int prow = pw_base + (m * 16 + 2 * quad + (r & 1) + 8 * ((r >> 1) & 1)) * 72;
        union { float f; unsigned u; } p0, p1, p2, p3;
        p0.f = __builtin_amdgcn_exp2f(sacc[m][0][r]);
        p1.f = __builtin_amdgcn_exp2f(sacc[m][1][r]);
        p2.f = __builtin_amdgcn_exp2f(sacc[m][2][r]);
        p3.f = __builtin_amdgcn_exp2f(sacc[m][3][r]);
        lrow[m][r] += (p0.f + p1.f) + (p2.f + p3.f);
        unsigned w01 = __builtin_amdgcn_perm(p1.u + 0x8000u, p0.u + 0x8000u, 0x07060302);
        unsigned w23 = __builtin_amdgcn_perm(p3.u + 0x8000u, p2.u + 0x8000u, 0x07060302);
        *(uint2*)(Ps + prow + row_in * 4) = make_uint2(w01, w23);
      }

    // O += P V over sigma-space (wave-private P rows -> no barrier)
    __builtin_amdgcn_s_setprio(1);
#pragma unroll
    for (int c = 0; c < 2; ++c) {
      bf16x8 ap0 = *(const bf16x8*)(Ps + pw_base + (permr) * 72 + c * 32 + quad * 8);
      bf16x8 ap1 = *(const bf16x8*)(Ps + pw_base + (16 + permr) * 72 + c * 32 + quad * 8);
#pragma unroll
      for (int t = 0; t < 4; ++t) {
        bf16x8 bv = *(const bf16x8*)(Vs + (t * 16 + row_in) * 72 + c * 32 + quad * 8);
        oacc[0][t] = __builtin_amdgcn_mfma_f32_16x16x32_bf16(ap0, bv, oacc[0][t], 0, 0, 0);
        oacc[1][t] = __builtin_amdgcn_mfma_f32_16x16x32_bf16(ap1, bv, oacc[1][t], 0, 0, 0);
      }
    }
    __builtin_amdgcn_s_setprio(0);
  }

#pragma unroll
  for (int m = 0; m < 2; ++m)
#pragma unroll
    for (int r = 0; r < 4; ++r) {
#pragma unroll
      for (int s = 1; s < 16; s <<= 1) lrow[m][r] += __shfl_xor(lrow[m][r], s, 64);
      float inv = 1.0f / lrow[m][r];
#pragma unroll
      for (int t = 0; t < 4; ++t)
        AO[qbase + (size_t)(w * 32 + m * 16 + quad * 4 + r) * DD + t * 16 + row_in] =
            f2bf(oacc[m][t][r] * inv);
    }
}

extern "C" void kernel_launch(void* const* d_in, const int* in_sizes, int n_in,
                              void* d_out, int out_size, void* d_ws, size_t ws_size,
                              hipStream_t stream) {
  const float* X  = (const float*)d_in[0];
  const float* Wq = (const float*)d_in[1];
  const float* Wk = (const float*)d_in[2];
  const float* Wv = (const float*)d_in[3];
  const float* Wo = (const float*)d_in[4];

  unsigned short* ws   = (unsigned short*)d_ws;
  unsigned short* Qb   = ws;                           // 16 MiB — also AO
  unsigned short* Kb   = Qb + (size_t)MM * DD;         // 16 MiB
  unsigned short* Vtb  = Kb + (size_t)MM * DD;         // 16 MiB, [bh][d][sigma(s)]
  unsigned short* Wall = Vtb + (size_t)MM * DD;        // 8 MiB (Wq,Wk,Wv,Wo bf16)
  unsigned short* Xb   = (unsigned short*)d_out;       // 16 MiB scratch inside d_out
  float* out = (float*)d_out;

  convall<<<dim3(1024, 12), 256, 0, stream>>>(X, Wq, Wk, Wv, Wo, Wall, Xb);

  gemm_k<3><<<dim3(MM / 128, 24), 256, 0, stream>>>(Xb, Wall, Qb, Kb, Vtb);

  attn_kernel<<<dim3(SS / 128, BB * HH), 256, 0, stream>>>(Qb, Kb, Vtb, Qb);

  gemm_k<1><<<dim3(MM / 128, 8), 256, 0, stream>>>(Qb, Wall + (size_t)3 * 1048576,
                                                   out, nullptr, nullptr);
}

// Round 5
// 263.209 us; speedup vs baseline: 1.2480x; 1.0180x over previous
//
#include <hip/hip_runtime.h>
#include <hip/hip_bf16.h>

#define BB 4
#define SS 2048
#define DD 1024
#define HH 16
#define MM (BB * SS)   // 8192

typedef __attribute__((ext_vector_type(8))) short bf16x8;
typedef __attribute__((ext_vector_type(4))) float f32x4;

__device__ __forceinline__ unsigned short f2bf(float f) {
  union { float f; unsigned u; } v; v.f = f;
  unsigned r = v.u + 0x7fffu + ((v.u >> 16) & 1u);
  return (unsigned short)(r >> 16);
}

__device__ __forceinline__ void gl2lds16(const void* g, void* l) {
  __builtin_amdgcn_global_load_lds(
      (const __attribute__((address_space(1))) unsigned int*)g,
      (__attribute__((address_space(3))) unsigned int*)l, 16, 0, 0);
}

// fp32 -> bf16 pre-convert: y<4 -> W[y] (1M each), y>=4 -> X chunk (8M total).
// Wq (y==0) is pre-scaled by log2e/8: folds the softmax 1/sqrt(DK) and ln->log2
// conversion into the QKV GEMM's Q output at zero cost (this kernel is HBM-bound).
__global__ __launch_bounds__(256)
void convall(const float* __restrict__ X, const float* __restrict__ a,
             const float* __restrict__ b, const float* __restrict__ c,
             const float* __restrict__ d, unsigned short* __restrict__ wall,
             unsigned short* __restrict__ xb) {
  int y = blockIdx.y;
  const float* s; unsigned short* o; float scl = 1.0f;
  if (y < 4) {
    const float* srcs[4] = {a, b, c, d};
    s = srcs[y]; o = wall + (size_t)y * 1048576;
    if (y == 0) scl = 0.180336880f;   // log2e / 8
  } else {
    s = X + (size_t)(y - 4) * 1048576; o = xb + (size_t)(y - 4) * 1048576;
  }
  int i = (blockIdx.x * 256 + threadIdx.x) * 4;
  float4 v = *(const float4*)(s + i);
  ushort4 h4;
  h4.x = f2bf(v.x * scl); h4.y = f2bf(v.y * scl);
  h4.z = f2bf(v.z * scl); h4.w = f2bf(v.w * scl);
  *(ushort4*)(o + i) = h4;
}

// C[m,n] = sum_k A[m,k]*W[n,k].  A bf16, B bf16, both staged via global_load_lds w=16.
// R5: T3 "minimum 2-phase" pipeline — double-buffered LDS staging, ONE barrier per
// K-step: {barrier -> STAGE(t+1 -> buf^1) -> ds_read+MFMA(buf)}.  The barrier's
// implicit vmcnt(0)/lgkmcnt(0) drain lands AFTER a full MFMA phase covered the
// in-flight global_load_lds, instead of immediately after issue (old structure
// serially exposed load latency every K-step: MfmaUtil 16%, VALUBusy 9%).
// OMODE 1: fp32 C.  OMODE 3: QKV routing (Q bf16 / K bf16 / V -> sigma-permuted V^T,
// Vt[bh][d][kt*64 + sigma(key)], sigma(key) = (key&15)*4 + (key>>4)).
template<int OMODE>
__global__ __launch_bounds__(256)
void gemm_k(const unsigned short* __restrict__ A16, const unsigned short* __restrict__ Bp,
            void* __restrict__ C0p, void* __restrict__ C1p, void* __restrict__ C2p) {
  __shared__ unsigned short As[2 * 4096];  // dbuf staging [128][32]; also V^T transpose buf (4352 used)
  __shared__ unsigned short Bs[2 * 4096];
  const int m0 = blockIdx.x * 128, n0g = blockIdx.y * 128;
  const int tid = threadIdx.x, lane = tid & 63, wave = tid >> 6;
  const int wm = (wave & 1) * 64, wn = (wave >> 1) * 64;
  const int row_in = lane & 15, quad = lane >> 4;

  f32x4 acc[4][4] = {};

  // staging source pointers (advance by kb shorts per K-step)
  const int r = wave * 32 + (lane >> 2);
  const unsigned short* gB = Bp + (size_t)(n0g + r) * DD + (lane & 3) * 8;
  const unsigned short* gA = A16 + (size_t)(m0 + r) * DD + (lane & 3) * 8;

  // prologue: stage kb=0 into buf 0
  gl2lds16(gB, Bs + (wave * 32) * 32);
  gl2lds16(gB + (size_t)16 * DD, Bs + (wave * 32 + 16) * 32);
  gl2lds16(gA, As + (wave * 32) * 32);
  gl2lds16(gA + (size_t)16 * DD, As + (wave * 32 + 16) * 32);

  int cur = 0;
  for (int kb = 0; kb < DD; kb += 32) {
    __syncthreads();   // drains own vmcnt/lgkmcnt: buf[cur] staged; prior reads done
    if (kb + 32 < DD) {
      const int nx = (cur ^ 1) * 4096;
      gl2lds16(gB + kb + 32, Bs + nx + (wave * 32) * 32);
      gl2lds16(gB + kb + 32 + (size_t)16 * DD, Bs + nx + (wave * 32 + 16) * 32);
      gl2lds16(gA + kb + 32, As + nx + (wave * 32) * 32);
      gl2lds16(gA + kb + 32 + (size_t)16 * DD, As + nx + (wave * 32 + 16) * 32);
    }
    const int cb = cur * 4096;
    bf16x8 af[4], bfr[4];
#pragma unroll
    for (int i = 0; i < 4; ++i)
      af[i] = *(const bf16x8*)(As + cb + (wm + i * 16 + row_in) * 32 + quad * 8);
#pragma unroll
    for (int j = 0; j < 4; ++j)
      bfr[j] = *(const bf16x8*)(Bs + cb + (wn + j * 16 + row_in) * 32 + quad * 8);
    __builtin_amdgcn_s_setprio(1);
#pragma unroll
    for (int i = 0; i < 4; ++i)
#pragma unroll
      for (int j = 0; j < 4; ++j)
        acc[i][j] = __builtin_amdgcn_mfma_f32_16x16x32_bf16(af[i], bfr[j], acc[i][j], 0, 0, 0);
    __builtin_amdgcn_s_setprio(0);
    cur ^= 1;
  }
  __syncthreads();   // all reads of As/Bs done before epilogue (Ts aliases As)

  // C/D layout: col = lane&15, row = quad*4 + reg
  if (OMODE == 1) {
    float* Cout = (float*)C0p;
#pragma unroll
    for (int i = 0; i < 4; ++i)
#pragma unroll
      for (int j = 0; j < 4; ++j)
#pragma unroll
        for (int r2 = 0; r2 < 4; ++r2)
          Cout[(size_t)(m0 + wm + i * 16 + quad * 4 + r2) * DD + n0g + wn + j * 16 + row_in] =
              acc[i][j][r2];
  } else {
    const int seg = n0g >> 10;
    if (seg < 2) {
      unsigned short* Cout = (unsigned short*)(seg == 0 ? C0p : C1p);
      const int n0 = n0g & 1023;
#pragma unroll
      for (int i = 0; i < 4; ++i)
#pragma unroll
        for (int j = 0; j < 4; ++j)
#pragma unroll
          for (int r2 = 0; r2 < 4; ++r2)
            Cout[(size_t)(m0 + wm + i * 16 + quad * 4 + r2) * DD + n0 + wn + j * 16 + row_in] =
                f2bf(acc[i][j][r2]);
    } else {
      // V^T epilogue -> Vt[bh][d][kt*64 + sigma(key)].  Stored position p holds
      // key sigma^-1(p) = (p&3)*16 + (p>>2): gather cols from the transpose buffer.
      unsigned short* Vt = (unsigned short*)C2p;
      unsigned short* Ts = As;
      const int b = m0 >> 11, m_in_b = m0 & 2047;
      const int nv = n0g - 2048;
#pragma unroll
      for (int cn = 0; cn < 4; ++cn) {
        if ((wave >> 1) == (cn >> 1)) {
#pragma unroll
          for (int i = 0; i < 4; ++i)
#pragma unroll
            for (int jj = 0; jj < 2; ++jj)
#pragma unroll
              for (int r2 = 0; r2 < 4; ++r2) {
                int j = (cn & 1) * 2 + jj;
                Ts[(jj * 16 + row_in) * 136 + wm + i * 16 + quad * 4 + r2] = f2bf(acc[i][j][r2]);
              }
        }
        __syncthreads();
#pragma unroll
        for (int it = 0; it < 2; ++it) {
          int cc = tid + it * 256;
          int rowL = cc >> 4, o8 = (cc & 15) * 8;
          int cbase = rowL * 136 + (o8 & 64) + ((o8 & 63) >> 2);
          ushort4 lo, hi;
          lo.x = Ts[cbase];      lo.y = Ts[cbase + 16];
          lo.z = Ts[cbase + 32]; lo.w = Ts[cbase + 48];
          hi.x = Ts[cbase + 1];  hi.y = Ts[cbase + 17];
          hi.z = Ts[cbase + 33]; hi.w = Ts[cbase + 49];
          int n = nv + cn * 32 + rowL;
          int h = n >> 6, dd = n & 63;
          unsigned short* dst = Vt + ((size_t)((b * 16 + h) * 64 + dd)) * SS + m_in_b + o8;
          *(ushort4*)dst = lo;
          *(ushort4*)(dst + 4) = hi;
        }
        __syncthreads();
      }
    }
  }
}

// Flash attention R4 shell (unchanged): 128 q-rows/block, 4 waves x 32 q, 4 blocks/CU.
// Q arrives pre-scaled by log2e/8 (folded into Wq in convall); p = exp2(sacc) directly.
// P->bf16 pack via bias-add + v_perm (NOT inline-asm cvt_pk: m240 measured -37%).
// V sigma-pre-permuted in global; wave-private P stripes; AO in-place over Q.
__global__ __launch_bounds__(256, 4)
void attn_kernel(const unsigned short* __restrict__ Q, const unsigned short* __restrict__ K,
                 const unsigned short* __restrict__ Vt_g, unsigned short* __restrict__ AO) {
  __shared__ unsigned short Ks[64 * 72];   // [key][d]
  __shared__ unsigned short Vs[64 * 72];   // [d][sigma(key)]
  __shared__ unsigned short Ps[128 * 72];  // [q perm][sigma(key)]
  // linear dispatch id (x-fastest); xcd = L&7 is the HW round-robin slot.
  // qt = j&15, bh = (L&7) + 8*(j>>4)  (bijective; all qt of a bh share L mod 8)
  const int L = (blockIdx.y << 4) + blockIdx.x;
  const int jj = L >> 3;
  const int qt = jj & 15;
  const int bh = (L & 7) + ((jj >> 4) << 3);
  const int b = bh >> 4, h = bh & 15;
  const int tid = threadIdx.x, lane = tid & 63, w = tid >> 6;
  const int row_in = lane & 15, quad = lane >> 4;
  const size_t qbase = ((size_t)(b * SS + qt * 128)) * DD + h * 64;

  bf16x8 aq[2][2];
#pragma unroll
  for (int m = 0; m < 2; ++m) {
    const unsigned short* qp = Q + qbase + (size_t)(w * 32 + m * 16 + row_in) * DD;
    aq[m][0] = *(const bf16x8*)(qp + quad * 8);
    aq[m][1] = *(const bf16x8*)(qp + 32 + quad * 8);
  }
  f32x4 oacc[2][4] = {};
  float lrow[2][4] = {};
  const int permr = 2 * (row_in >> 2) + (row_in & 1) + 8 * ((row_in >> 1) & 1);
  const int pw_base = (w * 32) * 72;

  // staging coords (thread-invariant): chunk c -> r = c>>3, o8 = (c&7)*8
  const int r0 = tid >> 3, o80 = (tid & 7) * 8;
  const int r1 = (tid + 256) >> 3, o81 = o80;  // (tid+256)&7 == tid&7
  const unsigned short* kp0 = K + ((size_t)(b * SS + r0)) * DD + h * 64 + o80;
  const unsigned short* kp1 = K + ((size_t)(b * SS + r1)) * DD + h * 64 + o81;
  const unsigned short* vp0 = Vt_g + ((size_t)(bh * 64 + r0)) * SS + o80;
  const unsigned short* vp1 = Vt_g + ((size_t)(bh * 64 + r1)) * SS + o81;

  // prologue prefetch kt=0
  uint4 kr0 = *(const uint4*)kp0;
  uint4 kr1 = *(const uint4*)kp1;
  uint4 vr0 = *(const uint4*)vp0;
  uint4 vr1 = *(const uint4*)vp1;

  for (int kt = 0; kt < SS / 64; ++kt) {
    __syncthreads();               // all waves done reading Ks/Vs of kt-1
    *(uint4*)(Ks + r0 * 72 + o80) = kr0;
    *(uint4*)(Ks + r1 * 72 + o81) = kr1;
    *(uint4*)(Vs + r0 * 72 + o80) = vr0;
    *(uint4*)(Vs + r1 * 72 + o81) = vr1;
    __syncthreads();               // staging visible
    if (kt + 1 < SS / 64) {
      // issue kt+1 loads now; they fly under the whole compute phase
      const size_t ko = (size_t)(kt + 1) * 64 * DD;
      const size_t vo = (size_t)(kt + 1) * 64;
      kr0 = *(const uint4*)(kp0 + ko);
      kr1 = *(const uint4*)(kp1 + ko);
      vr0 = *(const uint4*)(vp0 + vo);
      vr1 = *(const uint4*)(vp1 + vo);
    }

    // S = Q K^T : 32q x 64key per wave (Q carries the log2e/8 scale)
    f32x4 sacc[2][4] = {};
    __builtin_amdgcn_s_setprio(1);
#pragma unroll
    for (int n = 0; n < 4; ++n) {
      bf16x8 bk0 = *(const bf16x8*)(Ks + (n * 16 + row_in) * 72 + quad * 8);
      bf16x8 bk1 = *(const bf16x8*)(Ks + (n * 16 + row_in) * 72 + 32 + quad * 8);
#pragma unroll
      for (int m = 0; m < 2; ++m) {
        sacc[m][n] = __builtin_amdgcn_mfma_f32_16x16x32_bf16(aq[m][0], bk0, sacc[m][n], 0, 0, 0);
        sacc[m][n] = __builtin_amdgcn_mfma_f32_16x16x32_bf16(aq[m][1], bk1, sacc[m][n], 0, 0, 0);
      }
    }
    __builtin_amdgcn_s_setprio(0);

    // softmax: p = exp2(s); writer's keys {n*16+row_in} land at sigma = row_in*4+n
    // -> one b64 write per (m,r)
#pragma unroll
    for (int m = 0; m < 2; ++m)
#pragma unroll
      for (int r = 0; r < 4; ++r) {
        int prow = pw_base + (m * 16 + 2 * quad + (r & 1) + 8 * ((r >> 1) & 1)) * 72;
        union { float f; unsigned u; } p0, p1, p2, p3;
        p0.f = __builtin_amdgcn_exp2f(sacc[m][0][r]);
        p1.f = __builtin_amdgcn_exp2f(sacc[m][1][r]);
        p2.f = __builtin_amdgcn_exp2f(sacc[m][2][r]);
        p3.f = __builtin_amdgcn_exp2f(sacc[m][3][r]);
        lrow[m][r] += (p0.f + p1.f) + (p2.f + p3.f);
        unsigned w01 = __builtin_amdgcn_perm(p1.u + 0x8000u, p0.u + 0x8000u, 0x07060302);
        unsigned w23 = __builtin_amdgcn_perm(p3.u + 0x8000u, p2.u + 0x8000u, 0x07060302);
        *(uint2*)(Ps + prow + row_in * 4) = make_uint2(w01, w23);
      }

    // O += P V over sigma-space (wave-private P rows -> no barrier)
    __builtin_amdgcn_s_setprio(1);
#pragma unroll
    for (int c = 0; c < 2; ++c) {
      bf16x8 ap0 = *(const bf16x8*)(Ps + pw_base + (permr) * 72 + c * 32 + quad * 8);
      bf16x8 ap1 = *(const bf16x8*)(Ps + pw_base + (16 + permr) * 72 + c * 32 + quad * 8);
#pragma unroll
      for (int t = 0; t < 4; ++t) {
        bf16x8 bv = *(const bf16x8*)(Vs + (t * 16 + row_in) * 72 + c * 32 + quad * 8);
        oacc[0][t] = __builtin_amdgcn_mfma_f32_16x16x32_bf16(ap0, bv, oacc[0][t], 0, 0, 0);
        oacc[1][t] = __builtin_amdgcn_mfma_f32_16x16x32_bf16(ap1, bv, oacc[1][t], 0, 0, 0);
      }
    }
    __builtin_amdgcn_s_setprio(0);
  }

#pragma unroll
  for (int m = 0; m < 2; ++m)
#pragma unroll
    for (int r = 0; r < 4; ++r) {
#pragma unroll
      for (int s = 1; s < 16; s <<= 1) lrow[m][r] += __shfl_xor(lrow[m][r], s, 64);
      float inv = 1.0f / lrow[m][r];
#pragma unroll
      for (int t = 0; t < 4; ++t)
        AO[qbase + (size_t)(w * 32 + m * 16 + quad * 4 + r) * DD + t * 16 + row_in] =
            f2bf(oacc[m][t][r] * inv);
    }
}

extern "C" void kernel_launch(void* const* d_in, const int* in_sizes, int n_in,
                              void* d_out, int out_size, void* d_ws, size_t ws_size,
                              hipStream_t stream) {
  const float* X  = (const float*)d_in[0];
  const float* Wq = (const float*)d_in[1];
  const float* Wk = (const float*)d_in[2];
  const float* Wv = (const float*)d_in[3];
  const float* Wo = (const float*)d_in[4];

  unsigned short* ws   = (unsigned short*)d_ws;
  unsigned short* Qb   = ws;                           // 16 MiB — also AO
  unsigned short* Kb   = Qb + (size_t)MM * DD;         // 16 MiB
  unsigned short* Vtb  = Kb + (size_t)MM * DD;         // 16 MiB, [bh][d][sigma(s)]
  unsigned short* Wall = Vtb + (size_t)MM * DD;        // 8 MiB (Wq,Wk,Wv,Wo bf16)
  unsigned short* Xb   = (unsigned short*)d_out;       // 16 MiB scratch inside d_out
  float* out = (float*)d_out;

  convall<<<dim3(1024, 12), 256, 0, stream>>>(X, Wq, Wk, Wv, Wo, Wall, Xb);

  gemm_k<3><<<dim3(MM / 128, 24), 256, 0, stream>>>(Xb, Wall, Qb, Kb, Vtb);

  attn_kernel<<<dim3(SS / 128, BB * HH), 256, 0, stream>>>(Qb, Kb, Vtb, Qb);

  gemm_k<1><<<dim3(MM / 128, 8), 256, 0, stream>>>(Qb, Wall + (size_t)3 * 1048576,
                                                   out, nullptr, nullptr);
}